// Round 1
// baseline (292.539 us; speedup 1.0000x reference)
//
#include <hip/hip_runtime.h>
#include <hip/hip_bf16.h>

#define HID 64

__device__ __forceinline__ float bf2f(unsigned short x) {
    return __uint_as_float(((unsigned int)x) << 16);
}

__device__ __forceinline__ unsigned short f2bf(float f) {
    // round-to-nearest-even bf16
    unsigned int u = __float_as_uint(f);
    unsigned int r = (u + 0x7FFFu + ((u >> 16) & 1u)) >> 16;
    return (unsigned short)r;
}

// Kernel 1: per-node projections.
//   A[n][j] = sum_k z[n][k] * W1[k][j]
//   B[n][j] = sum_k z[n][k] * W1[64+k][j] + b1[j]
// Wave parity picks the half (stride is even so it is constant per wave).
// Each lane holds one W1 column (64 floats) in registers; z row is read with
// wave-uniform float4 loads (broadcast, 1 transaction each).
__global__ __launch_bounds__(256) void node_proj_kernel(
    const float* __restrict__ z, const float* __restrict__ W1,
    const float* __restrict__ b1,
    unsigned short* __restrict__ A, unsigned short* __restrict__ B,
    int n_nodes)
{
    const int tid    = blockIdx.x * blockDim.x + threadIdx.x;
    const int lane   = tid & 63;
    const int wave   = tid >> 6;
    const int nwaves = (gridDim.x * blockDim.x) >> 6;
    const int half   = wave & 1;          // 0 -> A, 1 -> B
    const int pair   = wave >> 1;
    const int npairs = nwaves >> 1;

    float w[HID];
#pragma unroll
    for (int k = 0; k < HID; ++k)
        w[k] = W1[(half * HID + k) * HID + lane];
    const float bias = half ? b1[lane] : 0.0f;
    unsigned short* __restrict__ dst = half ? B : A;

    for (int n = pair; n < n_nodes; n += npairs) {
        const float4* zr = (const float4*)(z + (size_t)n * HID);
        float acc = bias;
#pragma unroll
        for (int k4 = 0; k4 < HID / 4; ++k4) {
            float4 zv = zr[k4];           // uniform across lanes -> broadcast
            acc = fmaf(zv.x, w[4 * k4 + 0], acc);
            acc = fmaf(zv.y, w[4 * k4 + 1], acc);
            acc = fmaf(zv.z, w[4 * k4 + 2], acc);
            acc = fmaf(zv.w, w[4 * k4 + 3], acc);
        }
        dst[(size_t)n * HID + lane] = f2bf(acc);
    }
}

// Kernel 2: per-edge  out[e] = relu(A[row[e]] + B[col[e]]) . W2 + b2
// 64 edges per wave chunk: coalesced index loads, then 16 groups of 4 edges.
// Each 16-lane group covers one edge's 64 dims as ushort4 (8B/lane) gathers.
__global__ __launch_bounds__(256) void edge_kernel(
    const int* __restrict__ row, const int* __restrict__ col,
    const unsigned short* __restrict__ A, const unsigned short* __restrict__ B,
    const float* __restrict__ W2, const float* __restrict__ b2,
    float* __restrict__ out, int E)
{
    const int tid    = blockIdx.x * blockDim.x + threadIdx.x;
    const int lane   = tid & 63;
    const int gwave  = tid >> 6;
    const int nwaves = (gridDim.x * blockDim.x) >> 6;
    const int sub    = lane >> 4;   // 0..3: which edge of the group of 4
    const int l16    = lane & 15;   // dim slice: dims l16*4 .. l16*4+3

    const float4 w2v = ((const float4*)W2)[l16];
    const float  b2v = b2[0];

    const int nchunks = (E + 63) >> 6;
    for (int ch = gwave; ch < nchunks; ch += nwaves) {
        const int ebase = ch << 6;
        const int eidx  = ebase + lane;
        int r = 0, c = 0;
        if (eidx < E) { r = row[eidx]; c = col[eidx]; }

#pragma unroll
        for (int g = 0; g < 16; ++g) {
            const int src = g * 4 + sub;         // edge-in-chunk this group does
            const int ri = __shfl(r, src);
            const int ci = __shfl(c, src);

            const ushort4 a4 = *(const ushort4*)(A + (size_t)ri * HID + l16 * 4);
            const ushort4 b4 = *(const ushort4*)(B + (size_t)ci * HID + l16 * 4);

            float s0 = fmaxf(bf2f(a4.x) + bf2f(b4.x), 0.0f);
            float s1 = fmaxf(bf2f(a4.y) + bf2f(b4.y), 0.0f);
            float s2 = fmaxf(bf2f(a4.z) + bf2f(b4.z), 0.0f);
            float s3 = fmaxf(bf2f(a4.w) + bf2f(b4.w), 0.0f);

            float acc = s0 * w2v.x;
            acc = fmaf(s1, w2v.y, acc);
            acc = fmaf(s2, w2v.z, acc);
            acc = fmaf(s3, w2v.w, acc);

            // reduce across the 16-lane group
            acc += __shfl_xor(acc, 8);
            acc += __shfl_xor(acc, 4);
            acc += __shfl_xor(acc, 2);
            acc += __shfl_xor(acc, 1);

            const int eout = ebase + src;
            if (l16 == 0 && eout < E) out[eout] = acc + b2v;
        }
    }
}

extern "C" void kernel_launch(void* const* d_in, const int* in_sizes, int n_in,
                              void* d_out, int out_size, void* d_ws, size_t ws_size,
                              hipStream_t stream) {
    const float* z  = (const float*)d_in[0];
    const int*   ei = (const int*)d_in[1];
    const float* W1 = (const float*)d_in[2];
    const float* b1 = (const float*)d_in[3];
    const float* W2 = (const float*)d_in[4];
    const float* b2 = (const float*)d_in[5];
    float* out = (float*)d_out;

    const int n_nodes = in_sizes[0] / HID;     // 100000
    const int E       = in_sizes[1] / 2;       // 3200000
    const int* row = ei;
    const int* col = ei + E;

    unsigned short* A = (unsigned short*)d_ws;                 // [n_nodes][64] bf16
    unsigned short* B = A + (size_t)n_nodes * HID;             // [n_nodes][64] bf16

    node_proj_kernel<<<1024, 256, 0, stream>>>(z, W1, b1, A, B, n_nodes);
    edge_kernel<<<2048, 256, 0, stream>>>(row, col, A, B, W2, b2, out, E);
}

// Round 2
// 235.873 us; speedup vs baseline: 1.2402x; 1.2402x over previous
//
#include <hip/hip_runtime.h>
#include <hip/hip_bf16.h>

#define HID 64

__device__ __forceinline__ float bf2f(unsigned short x) {
    return __uint_as_float(((unsigned int)x) << 16);
}

__device__ __forceinline__ unsigned short f2bf(float f) {
    // round-to-nearest-even bf16
    unsigned int u = __float_as_uint(f);
    unsigned int r = (u + 0x7FFFu + ((u >> 16) & 1u)) >> 16;
    return (unsigned short)r;
}

// Kernel 1: per-node projections.
//   A[n][j] = sum_k z[n][k] * W1[k][j]
//   B[n][j] = sum_k z[n][k] * W1[64+k][j] + b1[j]
// Lane = output column j. Wave parity picks the A/B half. The node index is
// forced wave-uniform with readfirstlane so the z-row reads become s_load
// (SMEM/constant-cache) instead of per-lane vector loads: the 64 scalars sit
// in SGPRs and feed v_fmac directly. 4 partial accumulators break the FMA
// dependency chain (throughput 2cy, latency 4cy).
__global__ __launch_bounds__(256) void node_proj_kernel(
    const float* __restrict__ z, const float* __restrict__ W1,
    const float* __restrict__ b1,
    unsigned short* __restrict__ A, unsigned short* __restrict__ B,
    int n_nodes)
{
    const int tid    = blockIdx.x * blockDim.x + threadIdx.x;
    const int lane   = tid & 63;
    const int wave   = tid >> 6;
    const int nwaves = (gridDim.x * blockDim.x) >> 6;
    const int half   = wave & 1;          // 0 -> A, 1 -> B
    const int pair   = wave >> 1;
    const int npairs = nwaves >> 1;

    float w[HID];
#pragma unroll
    for (int k = 0; k < HID; ++k)
        w[k] = W1[(half * HID + k) * HID + lane];
    const float bias = half ? b1[lane] : 0.0f;
    unsigned short* __restrict__ dst = half ? B : A;

    for (int n = pair; n < n_nodes; n += npairs) {
        const int nu = __builtin_amdgcn_readfirstlane(n);   // provably uniform
        const float* __restrict__ zr = z + (size_t)nu * HID;
        float a0 = bias, a1 = 0.f, a2 = 0.f, a3 = 0.f;
#pragma unroll
        for (int k4 = 0; k4 < HID / 4; ++k4) {
            a0 = fmaf(zr[4 * k4 + 0], w[4 * k4 + 0], a0);
            a1 = fmaf(zr[4 * k4 + 1], w[4 * k4 + 1], a1);
            a2 = fmaf(zr[4 * k4 + 2], w[4 * k4 + 2], a2);
            a3 = fmaf(zr[4 * k4 + 3], w[4 * k4 + 3], a3);
        }
        dst[(size_t)nu * HID + lane] = f2bf((a0 + a1) + (a2 + a3));
    }
}

// Kernel 2: per-edge  out[e] = relu(A[row[e]] + B[col[e]]) . W2 + b2
// 64 edges per wave chunk. 8-lane groups, 8 edges per g-iteration; each lane
// gathers a uint4 (16B = 8 bf16 dims) of its group's A/B rows. All 16 gathers
// for the chunk are issued before any consumption (16-deep MLP per wave).
// E is a multiple of 64 so no bounds checks.
__global__ __launch_bounds__(256) void edge_kernel(
    const int* __restrict__ row, const int* __restrict__ col,
    const unsigned short* __restrict__ A, const unsigned short* __restrict__ B,
    const float* __restrict__ W2, const float* __restrict__ b2,
    float* __restrict__ out, int E)
{
    const int tid    = blockIdx.x * blockDim.x + threadIdx.x;
    const int lane   = tid & 63;
    const int gwave  = tid >> 6;
    const int nwaves = (gridDim.x * blockDim.x) >> 6;
    const int sub    = lane >> 3;   // 0..7: which edge of the group of 8
    const int l8     = lane & 7;    // dim slice: dims l8*8 .. l8*8+7

    float w2r[8];
#pragma unroll
    for (int i = 0; i < 8; ++i) w2r[i] = W2[l8 * 8 + i];
    const float b2v = b2[0];

    const int nchunks = E >> 6;
    for (int ch = gwave; ch < nchunks; ch += nwaves) {
        const int ebase = ch << 6;
        const int r = row[ebase + lane];   // coalesced
        const int c = col[ebase + lane];

        uint4 av[8], bv[8];
#pragma unroll
        for (int g = 0; g < 8; ++g) {
            const int ri = __shfl(r, g * 8 + sub);
            const int ci = __shfl(c, g * 8 + sub);
            av[g] = *(const uint4*)(A + (size_t)ri * HID + l8 * 8);
            bv[g] = *(const uint4*)(B + (size_t)ci * HID + l8 * 8);
        }

#pragma unroll
        for (int g = 0; g < 8; ++g) {
            const unsigned int* au = (const unsigned int*)&av[g];
            const unsigned int* bu = (const unsigned int*)&bv[g];
            float acc = 0.f;
#pragma unroll
            for (int i = 0; i < 4; ++i) {
                // uint = (bf16 dim 2i) | (bf16 dim 2i+1 << 16)
                float alo = __uint_as_float(au[i] << 16);
                float ahi = __uint_as_float(au[i] & 0xffff0000u);
                float blo = __uint_as_float(bu[i] << 16);
                float bhi = __uint_as_float(bu[i] & 0xffff0000u);
                float slo = fmaxf(alo + blo, 0.f);
                float shi = fmaxf(ahi + bhi, 0.f);
                acc = fmaf(slo, w2r[2 * i + 0], acc);
                acc = fmaf(shi, w2r[2 * i + 1], acc);
            }
            // reduce across the 8-lane group
            acc += __shfl_xor(acc, 4);
            acc += __shfl_xor(acc, 2);
            acc += __shfl_xor(acc, 1);
            if (l8 == 0) out[ebase + g * 8 + sub] = acc + b2v;
        }
    }
}

extern "C" void kernel_launch(void* const* d_in, const int* in_sizes, int n_in,
                              void* d_out, int out_size, void* d_ws, size_t ws_size,
                              hipStream_t stream) {
    const float* z  = (const float*)d_in[0];
    const int*   ei = (const int*)d_in[1];
    const float* W1 = (const float*)d_in[2];
    const float* b1 = (const float*)d_in[3];
    const float* W2 = (const float*)d_in[4];
    const float* b2 = (const float*)d_in[5];
    float* out = (float*)d_out;

    const int n_nodes = in_sizes[0] / HID;     // 100000
    const int E       = in_sizes[1] / 2;       // 3200000
    const int* row = ei;
    const int* col = ei + E;

    unsigned short* A = (unsigned short*)d_ws;                 // [n_nodes][64] bf16
    unsigned short* B = A + (size_t)n_nodes * HID;             // [n_nodes][64] bf16

    node_proj_kernel<<<2048, 256, 0, stream>>>(z, W1, b1, A, B, n_nodes);
    edge_kernel<<<2048, 256, 0, stream>>>(row, col, A, B, W2, b2, out, E);
}